// Round 2
// baseline (5669.072 us; speedup 1.0000x reference)
//
#include <hip/hip_runtime.h>

typedef unsigned short u16;
typedef __attribute__((ext_vector_type(8))) short bf16x8;
typedef __attribute__((ext_vector_type(4))) float f32x4;

#define B_   128
#define T_   512
#define NOBS 256
#define H_   512
#define G4   2048
#define NACT 32
#define M_   (B_*T_)   // 65536

__device__ __forceinline__ float b2f(u16 s) {
  union { unsigned u; float f; } v; v.u = ((unsigned)s) << 16; return v.f;
}
__device__ __forceinline__ u16 f2b(float f) {
  union { float f; unsigned u; } v; v.f = f;
  unsigned r = v.u + 0x7FFFu + ((v.u >> 16) & 1u);
  return (u16)(r >> 16);
}
__device__ __forceinline__ float sigm(float x) { return 1.f/(1.f+__expf(-x)); }
__device__ __forceinline__ float tanh_f(float x) { return 1.f - 2.f/(1.f+__expf(2.f*x)); }

// global -> LDS direct copy, 16B per lane. ldsbase wave-uniform; HW adds lane*16.
__device__ __forceinline__ void gld16(const void* g, void* ldsbase) {
#if __has_builtin(__builtin_amdgcn_global_load_lds)
  __builtin_amdgcn_global_load_lds((const __attribute__((address_space(1))) void*)g,
                                   (__attribute__((address_space(3))) void*)ldsbase, 16, 0, 0);
#else
  ((float4*)ldsbase)[threadIdx.x & 63] = *(const float4*)g;
#endif
}

// ---------------- prep kernels ----------------
__global__ void k_cvt(const float* __restrict__ in, u16* __restrict__ out, int n4) {
  int stride = gridDim.x * blockDim.x;
  for (int i = blockIdx.x*blockDim.x + threadIdx.x; i < n4; i += stride) {
    float4 v = ((const float4*)in)[i];
    uint2 p;
    p.x = (unsigned)f2b(v.x) | ((unsigned)f2b(v.y) << 16);
    p.y = (unsigned)f2b(v.z) | ((unsigned)f2b(v.w) << 16);
    ((uint2*)out)[i] = p;
  }
}

// out (C,R) bf16 <- in (R,C) f32 :  out[c*R+r] = in[r*C+c]
__global__ void k_transpose(const float* __restrict__ in, u16* __restrict__ out, int R, int C) {
  int i = blockIdx.x*blockDim.x + threadIdx.x;
  if (i < R*C) {
    int c = i / R, r = i - c*R;
    out[i] = f2b(in[r*C + c]);
  }
}

// ---------------- GEMM: C(M,N) = A(M,K) @ BT(N,K)^T, bf16 in/out, f32 accum ----------------
// EPI 0: raw store; EPI 1: +bias, relu
template<int EPI>
__global__ __launch_bounds__(256) void k_gemm_bt(const u16* __restrict__ A, const u16* __restrict__ BT,
                                                 u16* __restrict__ C, const float* __restrict__ bias,
                                                 int M, int N, int K)
{
  __shared__ u16 As[128*64];
  __shared__ u16 Bs[128*64];
  const int tid = threadIdx.x, wv = tid >> 6, lane = tid & 63;
  const int ntile = N >> 7;
  const int tm = blockIdx.x / ntile, tn = blockIdx.x - tm*ntile;
  const int wr = wv >> 1, wc = wv & 1;
  f32x4 acc[4][4];
  for (int m=0;m<4;++m) for (int n=0;n<4;++n) acc[m][n] = (f32x4){0.f,0.f,0.f,0.f};
  const long abase = (long)tm*128, bbase = (long)tn*128;
  const int kit = K >> 6;
  for (int kt = 0; kt < kit; ++kt) {
    const int k0 = kt << 6;
    #pragma unroll
    for (int q = 0; q < 4; ++q) {
      int off = (wv*4+q)*1024 + lane*16;   // byte offset within 16KB tile
      int row = off >> 7, colb = off & 127;
      gld16((const char*)A  + ((abase+row)*K + k0)*2 + colb, (char*)As + (wv*4+q)*1024);
      gld16((const char*)BT + ((bbase+row)*K + k0)*2 + colb, (char*)Bs + (wv*4+q)*1024);
    }
    asm volatile("s_waitcnt vmcnt(0)" ::: "memory");
    __syncthreads();
    const int kg = (lane >> 4) * 8;
    #pragma unroll
    for (int kk = 0; kk < 64; kk += 32) {
      bf16x8 af[4], bfr[4];
      #pragma unroll
      for (int m = 0; m < 4; ++m)
        af[m] = *(const bf16x8*)(As + (wr*64 + m*16 + (lane&15))*64 + kk + kg);
      #pragma unroll
      for (int n = 0; n < 4; ++n)
        bfr[n] = *(const bf16x8*)(Bs + (wc*64 + n*16 + (lane&15))*64 + kk + kg);
      #pragma unroll
      for (int m = 0; m < 4; ++m)
        #pragma unroll
        for (int n = 0; n < 4; ++n)
          acc[m][n] = __builtin_amdgcn_mfma_f32_16x16x32_bf16(af[m], bfr[n], acc[m][n], 0, 0, 0);
    }
    __syncthreads();
  }
  const int rq = (lane >> 4) * 4, cl = lane & 15;
  #pragma unroll
  for (int n = 0; n < 4; ++n) {
    const int coln = (int)bbase + wc*64 + n*16 + cl;
    const float bv = (EPI == 1) ? bias[coln] : 0.f;
    #pragma unroll
    for (int m = 0; m < 4; ++m) {
      const long rowb = abase + wr*64 + m*16 + rq;
      #pragma unroll
      for (int q = 0; q < 4; ++q) {
        float v = acc[m][n][q];
        if (EPI == 1) v = fmaxf(v + bv, 0.f);
        C[(rowb+q)*(long)N + coln] = f2b(v);
      }
    }
  }
}

// ---------------- one LSTM timestep (x@Wx fused in) ----------------
// grid 128: wg = bg*32 + hsI ; bg owns batch rows [bg*32,+32), hsI owns hidden [hsI*16,+16)
// z = obs_t @ Wx + h @ Wh + b  for my 32 rows x 64 gate-cols; frags straight from L2.
__global__ __launch_bounds__(256) void k_lstm_step(
    const u16* __restrict__ obsb, const u16* __restrict__ WxT,
    const u16* __restrict__ WhT, const float* __restrict__ bvec,
    const u16* __restrict__ hcur, u16* __restrict__ hnxt,
    float* __restrict__ cbuf, u16* __restrict__ ys,
    float* __restrict__ outh, float* __restrict__ outc, int t)
{
  __shared__ float zs[32*64];
  const int tid = threadIdx.x, wv = tid >> 6, lane = tid & 63;
  const int wg = blockIdx.x, bg = wg >> 5, hsI = wg & 31;
  const int rb0 = bg*32, S0 = hsI*16;

  // prefetch per-thread epilogue operands (overlaps with MFMA below)
  float bv[2][4], cv[2];
  int rL[2], slL[2];
  #pragma unroll
  for (int p = 0; p < 2; ++p) {
    int idx = tid*2 + p;
    rL[p] = idx >> 4; slL[p] = idx & 15;
    #pragma unroll
    for (int g = 0; g < 4; ++g) bv[p][g] = bvec[g*H_ + S0 + slL[p]];
    cv[p] = cbuf[(rb0 + rL[p])*H_ + S0 + slL[p]];
  }

  const int r0w = (wv & 1)*16, c0w = (wv >> 1)*32;
  const int arow = rb0 + r0w + (lane & 15);
  const int kg8 = (lane >> 4)*8;
  const int j0 = c0w + (lane & 15), j1 = j0 + 16;
  const long w0 = (long)((j0 >> 4)*H_ + S0 + (j0 & 15));   // global gate-col of j0
  const long w1 = (long)((j1 >> 4)*H_ + S0 + (j1 & 15));

  f32x4 acc0 = {0.f,0.f,0.f,0.f}, acc1 = {0.f,0.f,0.f,0.f};

  // phase 1: obs_t @ Wx  (K = 256)
  {
    const u16* Ax  = obsb + ((long)arow*T_ + t)*NOBS + kg8;
    const u16* Bx0 = WxT + w0*NOBS + kg8;
    const u16* Bx1 = WxT + w1*NOBS + kg8;
    #pragma unroll
    for (int ks = 0; ks < 8; ++ks) {
      bf16x8 a  = *(const bf16x8*)(Ax  + ks*32);
      bf16x8 b0 = *(const bf16x8*)(Bx0 + ks*32);
      bf16x8 b1 = *(const bf16x8*)(Bx1 + ks*32);
      acc0 = __builtin_amdgcn_mfma_f32_16x16x32_bf16(a, b0, acc0, 0, 0, 0);
      acc1 = __builtin_amdgcn_mfma_f32_16x16x32_bf16(a, b1, acc1, 0, 0, 0);
    }
  }
  // phase 2: h @ Wh  (K = 512)
  {
    const u16* Ah  = hcur + arow*H_ + kg8;
    const u16* Bh0 = WhT + w0*H_ + kg8;
    const u16* Bh1 = WhT + w1*H_ + kg8;
    #pragma unroll
    for (int ks = 0; ks < 16; ++ks) {
      bf16x8 a  = *(const bf16x8*)(Ah  + ks*32);
      bf16x8 b0 = *(const bf16x8*)(Bh0 + ks*32);
      bf16x8 b1 = *(const bf16x8*)(Bh1 + ks*32);
      acc0 = __builtin_amdgcn_mfma_f32_16x16x32_bf16(a, b0, acc0, 0, 0, 0);
      acc1 = __builtin_amdgcn_mfma_f32_16x16x32_bf16(a, b1, acc1, 0, 0, 0);
    }
  }
  {
    const int zc = c0w + (lane & 15);
    const int zr0 = r0w + (lane >> 4)*4;   // C/D layout: col=lane&15, row=(lane>>4)*4+q [m89]
    #pragma unroll
    for (int q = 0; q < 4; ++q) {
      zs[(zr0+q)*64 + zc]      = acc0[q];
      zs[(zr0+q)*64 + zc + 16] = acc1[q];
    }
  }
  __syncthreads();

  #pragma unroll
  for (int p = 0; p < 2; ++p) {
    const int r = rL[p], sl = slL[p];
    const float zi = zs[r*64 + sl]      + bv[p][0];
    const float zf = zs[r*64 + 16 + sl] + bv[p][1];
    const float zg = zs[r*64 + 32 + sl] + bv[p][2];
    const float zo = zs[r*64 + 48 + sl] + bv[p][3];
    const float iv = sigm(zi), fv = sigm(zf), gv = tanh_f(zg), ov = sigm(zo);
    const float cn = fv*cv[p] + iv*gv;
    const float hn = ov*tanh_f(cn);
    const int gi = (rb0 + r)*H_ + S0 + sl;
    cbuf[gi] = cn;
    const u16 hb = f2b(hn);
    hnxt[gi] = hb;
    ys[((long)(rb0 + r)*T_ + t)*H_ + S0 + sl] = hb;
    if (t == T_-1) { outh[gi] = hn; outc[gi] = cn; }
  }
}

// ---------------- head: out = 0.5*(tanh(X@WoT^T + bo)*(amax-amin) + (amax+amin)) ----------------
__global__ __launch_bounds__(256) void k_head(const u16* __restrict__ X, const u16* __restrict__ WoT,
    const float* __restrict__ bo, const float* __restrict__ amin, const float* __restrict__ amax,
    float* __restrict__ out)
{
  __shared__ u16 Ws[NACT*H_];
  __shared__ float sc[3*NACT];
  const int tid = threadIdx.x;
  #pragma unroll
  for (int q = 0; q < 8; ++q)
    ((float4*)Ws)[q*256 + tid] = ((const float4*)WoT)[q*256 + tid];
  if (tid < NACT) { sc[tid] = bo[tid]; sc[NACT+tid] = amin[tid]; sc[2*NACT+tid] = amax[tid]; }
  __syncthreads();
  const long r = (long)blockIdx.x*64 + (tid >> 2);
  const int c0 = (tid & 3)*8;
  float acc[8];
  #pragma unroll
  for (int c = 0; c < 8; ++c) acc[c] = 0.f;
  const u16* Arow = X + r*H_;
  for (int kc = 0; kc < H_/8; ++kc) {
    bf16x8 a = *(const bf16x8*)(Arow + kc*8);
    float av[8];
    #pragma unroll
    for (int j = 0; j < 8; ++j) av[j] = b2f((u16)a[j]);
    #pragma unroll
    for (int c = 0; c < 8; ++c) {
      bf16x8 w = *(const bf16x8*)(Ws + (c0+c)*H_ + kc*8);
      #pragma unroll
      for (int j = 0; j < 8; ++j) acc[c] += av[j] * b2f((u16)w[j]);
    }
  }
  #pragma unroll
  for (int c = 0; c < 8; ++c) {
    const int cc = c0 + c;
    const float y = acc[c] + sc[cc];
    const float tv = tanhf(y);
    out[r*NACT + cc] = 0.5f*(tv*(sc[2*NACT+cc]-sc[NACT+cc]) + (sc[2*NACT+cc]+sc[NACT+cc]));
  }
}

extern "C" void kernel_launch(void* const* d_in, const int* in_sizes, int n_in,
                              void* d_out, int out_size, void* d_ws, size_t ws_size,
                              hipStream_t stream) {
  const float* obs = (const float*)d_in[0];
  const float* h0  = (const float*)d_in[1];
  const float* c0  = (const float*)d_in[2];
  const float* Wh  = (const float*)d_in[4];
  const float* Wx  = (const float*)d_in[3];
  const float* bb  = (const float*)d_in[5];
  const float* W1  = (const float*)d_in[6];
  const float* b1  = (const float*)d_in[7];
  const float* W2  = (const float*)d_in[8];
  const float* b2  = (const float*)d_in[9];
  const float* Wo  = (const float*)d_in[10];
  const float* bo  = (const float*)d_in[11];
  const float* amin= (const float*)d_in[12];
  const float* amax= (const float*)d_in[13];

  char* ws = (char*)d_ws;
  // workspace layout (bytes) — total ~164.5 MiB:
  //   obsb [0, 32MiB)            bf16 (B,T,NOBS)
  //   ys   [32MiB, 96MiB)        bf16 (B,T,H); dead after W1-GEMM
  //   t1   [96MiB, 160MiB)       bf16 (M,512)
  //   t2   = alias ys            bf16 (M,512); written by W2-GEMM (reads t1 only — disjoint)
  u16* obsb  = (u16*)(ws + 0);
  u16* ys    = (u16*)(ws + 33554432);
  u16* t1    = (u16*)(ws + 100663296);
  u16* t2    = (u16*)(ws + 33554432);          // alias: ys dead when written
  u16* WxT   = (u16*)(ws + 167772160);         // (G4, NOBS)  1 MiB
  u16* WhT   = (u16*)(ws + 168820736);         // (G4, H)     2 MiB
  u16* W1T   = (u16*)(ws + 170917888);         // (512, H)    0.5 MiB
  u16* W2T   = (u16*)(ws + 171442176);         // (512, 512)  0.5 MiB
  u16* WoT   = (u16*)(ws + 171966464);         // (NACT, H)   64 KiB
  u16* hb0   = (u16*)(ws + 171999232);         // 128 KiB
  u16* hb1   = (u16*)(ws + 172130304);         // 128 KiB
  float* cbuf= (float*)(ws + 172261376);       // 256 KiB -> end 172,523,520

  float* outA = (float*)d_out;
  float* outh = outA + (long)M_*NACT;
  float* outc = outh + B_*H_;

  // prep: bf16 conversions + weight transposes
  k_cvt<<<2048, 256, 0, stream>>>(obs, obsb, M_*NOBS/4);
  k_cvt<<<64,   256, 0, stream>>>(h0, hb0, B_*H_/4);
  hipMemcpyAsync(cbuf, c0, B_*H_*sizeof(float), hipMemcpyDeviceToDevice, stream);
  k_transpose<<<2048, 256, 0, stream>>>(Wx, WxT, NOBS, G4);
  k_transpose<<<4096, 256, 0, stream>>>(Wh, WhT, H_, G4);
  k_transpose<<<1024, 256, 0, stream>>>(W1, W1T, H_, H_);
  k_transpose<<<1024, 256, 0, stream>>>(W2, W2T, H_, H_);
  k_transpose<<<64,   256, 0, stream>>>(Wo, WoT, H_, NACT);

  // sequential LSTM scan, one launch per step (kernel boundary = global barrier)
  for (int t = 0; t < T_; ++t) {
    const u16* hc = (t & 1) ? hb1 : hb0;
    u16* hn = (t & 1) ? hb0 : hb1;
    k_lstm_step<<<128, 256, 0, stream>>>(obsb, WxT, WhT, bb, hc, hn, cbuf, ys, outh, outc, t);
  }

  // MLP head
  k_gemm_bt<1><<<(M_/128)*(H_/128), 256, 0, stream>>>(ys, W1T, t1, b1, M_, H_, H_);
  k_gemm_bt<1><<<(M_/128)*(H_/128), 256, 0, stream>>>(t1, W2T, t2, b2, M_, H_, H_);
  k_head<<<M_/64, 256, 0, stream>>>(t2, WoT, bo, amin, amax, outA);
}